// Round 4
// baseline (584.899 us; speedup 1.0000x reference)
//
#include <hip/hip_runtime.h>

#define VOCAB 21
#define EMB 128
#define H1 64
#define H2 100
#define T1 500
#define TP 100
#define NB 1024
#define TBL_LD 268   // words; 268*4 B stride; 268 mod 32 = 12 decorrelates banks

typedef __attribute__((ext_vector_type(8))) short bf16x8;
typedef __attribute__((ext_vector_type(4))) float f32x4;

__device__ __forceinline__ float sigf(float x){ return 1.0f/(1.0f+__expf(-x)); }
__device__ __forceinline__ float tanhf_(float x){ return 1.0f - 2.0f/(1.0f+__expf(2.0f*x)); }
__device__ __forceinline__ unsigned short f2bf(float x){
    union { float f; unsigned u; } v; v.f = x;
    return (unsigned short)((v.u + 0x8000u) >> 16);   // round-half-up, cheap
}
// LDS-only barrier: do NOT drain vmcnt (global stores fly async past it)
__device__ __forceinline__ void bar_lds(){
    asm volatile("s_waitcnt lgkmcnt(0)\n\ts_barrier" ::: "memory");
}

// ---------------------------------------------------------------------------
// Kernel 0: permuted xproj table. table[v][4*cell+gate] =
//   dot(W_ih1[gate*64+cell,:], emb[v,:]) + b_ih1[..] + b_hh1[..]
// ---------------------------------------------------------------------------
__global__ void k_table(const float* __restrict__ Wih, const float* __restrict__ emb,
                        const float* __restrict__ bih, const float* __restrict__ bhh,
                        float* __restrict__ table){
    const int p = threadIdx.x;           // permuted gate-col 0..255
    const int v = blockIdx.x;
    const int orig = (p & 3) * H1 + (p >> 2);
    float s = bih[orig] + bhh[orig];
    if (v != 0){
        const float* w = Wih + orig * EMB;
        const float* e = emb + v * EMB;
        #pragma unroll 16
        for (int d = 0; d < EMB; ++d) s += w[d]*e[d];
    }
    table[v*TBL_LD + p] = s;
}

// ---------------------------------------------------------------------------
// Kernel 1: layer-1 LSTM. 4 rows/block, 256 blocks, 8 waves.
// Wave w owns gate tiles {2w, 2w+1}. Register-direct cell update from MFMA acc
// (p = 4*cell+gate permutation). Rows 4..15 of the tile are junk (bounded,
// column-independent) — only global writes are masked. One LDS barrier/step.
// ---------------------------------------------------------------------------
__global__ __launch_bounds__(512, 2) void k_lstm1(
    const int* __restrict__ xidx, const float* __restrict__ Whh,
    const float* __restrict__ tbl_g, float* __restrict__ x2){
  __shared__ __align__(16) float table[VOCAB*TBL_LD];        // 22512 B
  __shared__ __align__(16) unsigned short hbuf[2][16*64];    // 4096 B, XOR-swizzled
  __shared__ int idxs[4*T1];                                 // 8000 B

  const int tid = threadIdx.x;
  const int w = tid >> 6, l = tid & 63;
  const int b0 = blockIdx.x * 4;
  const int row = l & 15, kg = l >> 4;

  for (int i = tid; i < VOCAB*TBL_LD; i += 512) table[i] = tbl_g[i];
  for (int i = tid; i < 4*T1; i += 512){
      int r = i / T1, t = i - r*T1;
      idxs[i] = xidx[(b0 + r)*T1 + t];
  }
  for (int i = tid; i < 16*64; i += 512) hbuf[0][i] = 0;     // t=0 reads buf 0

  // A fragments: tiles 2w+u; lane holds A row m=row, k = 32c + 8kg + j
  bf16x8 af[2][2];
  #pragma unroll
  for (int u = 0; u < 2; ++u){
      const int p = 16*(2*w + u) + row;
      const int orig = (p & 3)*H1 + (p >> 2);
      #pragma unroll
      for (int c = 0; c < 2; ++c){
          const float* src = Whh + orig*H1 + c*32 + kg*8;
          bf16x8 f;
          #pragma unroll
          for (int j = 0; j < 8; ++j) f[j] = (short)f2bf(src[j]);
          af[u][c] = f;
      }
  }

  const int cell0 = 8*w + kg, cell1 = cell0 + 4;  // acc tile 2w / 2w+1 cells
  char* hb = (char*)hbuf;
  const int swz = (row & 7) << 4;
  const int rb0 = (row*128 + 16*kg) ^ swz;
  const int rb1 = (row*128 + 64 + 16*kg) ^ swz;
  const int wb0 = (row*128 + 2*cell0) ^ swz;
  const int wb1 = (row*128 + 2*cell1) ^ swz;
  const int rowc = row & 3;                        // clamp -> broadcast table reads

  float cc0 = 0.f, cc1 = 0.f, pm0 = -1e30f, pm1 = -1e30f;
  __syncthreads();

  int v0 = idxs[rowc*T1];
  f32x4 tv0 = *(const f32x4*)&table[v0*TBL_LD + 4*cell0];
  f32x4 tv1 = *(const f32x4*)&table[v0*TBL_LD + 4*cell1];

  int rp = 0, tm = 0;
  for (int t = 0; t < T1; ++t){
      bf16x8 bf0 = *(const bf16x8*)(hb + rp + rb0);
      bf16x8 bf1 = *(const bf16x8*)(hb + rp + rb1);
      f32x4 a0 = __builtin_amdgcn_mfma_f32_16x16x32_bf16(af[0][0], bf0, tv0, 0,0,0);
      a0       = __builtin_amdgcn_mfma_f32_16x16x32_bf16(af[0][1], bf1, a0, 0,0,0);
      f32x4 a1 = __builtin_amdgcn_mfma_f32_16x16x32_bf16(af[1][0], bf0, tv1, 0,0,0);
      a1       = __builtin_amdgcn_mfma_f32_16x16x32_bf16(af[1][1], bf1, a1, 0,0,0);
      if (t + 1 < T1){                       // prefetch next xproj (idx-only dep)
          int vn = idxs[rowc*T1 + t + 1];
          tv0 = *(const f32x4*)&table[vn*TBL_LD + 4*cell0];
          tv1 = *(const f32x4*)&table[vn*TBL_LD + 4*cell1];
      }
      cc0 = sigf(a0[1])*cc0 + sigf(a0[0])*tanhf_(a0[2]);
      float h0 = sigf(a0[3])*tanhf_(cc0);
      cc1 = sigf(a1[1])*cc1 + sigf(a1[0])*tanhf_(a1[2]);
      float h1 = sigf(a1[3])*tanhf_(cc1);
      const int wp = rp ^ 2048;
      *(unsigned short*)(hb + wp + wb0) = f2bf(h0);
      *(unsigned short*)(hb + wp + wb1) = f2bf(h1);
      pm0 = fmaxf(pm0, h0); pm1 = fmaxf(pm1, h1);
      if (++tm == 5){
          if (row < 4){
              float* dst = x2 + (b0 + row)*(TP*H1) + (t/5)*H1;
              dst[cell0] = pm0; dst[cell1] = pm1;  // async, not drained by barrier
          }
          pm0 = -1e30f; pm1 = -1e30f; tm = 0;
      }
      rp = wp;
      bar_lds();
  }
}

// ---------------------------------------------------------------------------
// Kernel 2: layer-2 LSTM. 4 rows/block, 256 blocks, 8 waves; 26 gate tiles
// (cells padded to 104) split 4,4,3,3,3,3,3,3. B = [x(64) | h(100 pad 128)]
// bf16 ping-pong; stagers are waves 6,7 (light tiles). One LDS barrier/step.
// ---------------------------------------------------------------------------
__global__ __launch_bounds__(512, 2) void k_lstm2(
    const float* __restrict__ x2, const float* __restrict__ Wih,
    const float* __restrict__ Whh, const float* __restrict__ bih,
    const float* __restrict__ bhh, const float* __restrict__ fcw,
    const float* __restrict__ fcb, float* __restrict__ out){
  __shared__ __align__(16) unsigned short blds[2][16*192];   // 12288 B
  __shared__ float fcred[8][4];

  const int tid = threadIdx.x;
  const int w = tid >> 6, l = tid & 63;
  const int b0 = blockIdx.x * 4;
  const int row = l & 15, kg = l >> 4;
  const int tlo = (w < 2) ? 4*w : 8 + 3*(w - 2);
  const int nt  = (w < 2) ? 4 : 3;

  // zero h-region (k=64..191) of rows 0..3, buf 0 (512 threads cover 4*128)
  { int r = tid >> 7, k = 64 + (tid & 127); blds[0][r*192 + k] = 0; }

  // A fragments: [W_ih2 | W_hh2] permuted, zero-padded (k>=164 or cell>=100)
  bf16x8 af[4][6];
  #pragma unroll
  for (int u = 0; u < 4; ++u){
      if (u < nt){
          const int p = 16*(tlo + u) + row;
          const int cell = p >> 2, gate = p & 3;
          #pragma unroll
          for (int c = 0; c < 6; ++c){
              bf16x8 f;
              #pragma unroll
              for (int j = 0; j < 8; ++j){
                  int k = c*32 + kg*8 + j;
                  float vv = 0.f;
                  if (cell < H2){
                      if (k < 64)           vv = Wih[(gate*H2 + cell)*H1 + k];
                      else if (k < 64 + H2) vv = Whh[(gate*H2 + cell)*H2 + (k - 64)];
                  }
                  f[j] = (short)f2bf(vv);
              }
              af[u][c] = f;
          }
      }
  }

  int cellu[4];
  f32x4 bz[4];
  float fw[4];
  #pragma unroll
  for (int u = 0; u < 4; ++u){
      const int cu = 4*(tlo + u) + kg;
      cellu[u] = cu;
      f32x4 b = {0.f,0.f,0.f,0.f};
      float fv = 0.f;
      if (u < nt && cu < H2){
          #pragma unroll
          for (int g = 0; g < 4; ++g) b[g] = bih[g*H2 + cu] + bhh[g*H2 + cu];
          fv = fcw[cu];
      }
      bz[u] = b; fw[u] = fv;
  }

  char* bb = (char*)blds;
  const int swz = (row & 7) << 4;
  int rb[6];
  #pragma unroll
  for (int c = 0; c < 6; ++c) rb[c] = (row*384 + 64*c + 16*kg) ^ swz;
  int wbh[4];
  #pragma unroll
  for (int u = 0; u < 4; ++u) wbh[u] = (row*384 + 2*(64 + cellu[u])) ^ swz;

  // x-staging role: waves 6,7 (tid>=384): row xr, cells 2*xc, 2*xc+1
  const int xr = (tid >> 5) & 3, xc = tid & 31;
  const int xwb = (xr*384 + 4*xc) ^ (xr << 4);
  if (tid >= 384){                               // stage x(0) into buf 0
      float2 v = *(const float2*)&x2[(b0 + xr)*(TP*H1) + 2*xc];
      unsigned pk = (unsigned)f2bf(v.x) | ((unsigned)f2bf(v.y) << 16);
      *(unsigned*)(bb + xwb) = pk;
  }
  float cc[4] = {0.f,0.f,0.f,0.f};
  float hh[4] = {0.f,0.f,0.f,0.f};
  __syncthreads();

  int rp = 0;
  for (int t = 0; t < TP; ++t){
      float2 xn = {0.f, 0.f};
      if (tid >= 384 && t + 1 < TP)              // T14 issue-early
          xn = *(const float2*)&x2[(b0 + xr)*(TP*H1) + (t+1)*H1 + 2*xc];
      bf16x8 bf[6];
      #pragma unroll
      for (int c = 0; c < 6; ++c) bf[c] = *(const bf16x8*)(bb + rp + rb[c]);
      const int wp = rp ^ 6144;
      #pragma unroll
      for (int u = 0; u < 4; ++u){
          if (u < nt){
              f32x4 z = bz[u];
              #pragma unroll
              for (int c = 0; c < 6; ++c)
                  z = __builtin_amdgcn_mfma_f32_16x16x32_bf16(af[u][c], bf[c], z, 0,0,0);
              cc[u] = sigf(z[1])*cc[u] + sigf(z[0])*tanhf_(z[2]);
              float h = sigf(z[3])*tanhf_(cc[u]);
              hh[u] = h;
              *(unsigned short*)(bb + wp + wbh[u]) = f2bf(h);
          }
      }
      if (tid >= 384 && t + 1 < TP){             // write-late
          unsigned pk = (unsigned)f2bf(xn.x) | ((unsigned)f2bf(xn.y) << 16);
          *(unsigned*)(bb + wp + xwb) = pk;
      }
      rp = wp;
      bar_lds();
  }

  // FC + sigmoid: lane sum over its cells, reduce kg groups, then waves
  float p = 0.f;
  #pragma unroll
  for (int u = 0; u < 4; ++u) if (u < nt) p += hh[u] * fw[u];
  p += __shfl_xor(p, 16);
  p += __shfl_xor(p, 32);
  if (l < 4) fcred[w][l] = p;
  __syncthreads();
  if (tid < 4){
      float s = 0.f;
      #pragma unroll
      for (int ww = 0; ww < 8; ++ww) s += fcred[ww][tid];
      out[b0 + tid] = sigf(s + fcb[0]);
  }
}

// ---------------------------------------------------------------------------
extern "C" void kernel_launch(void* const* d_in, const int* in_sizes, int n_in,
                              void* d_out, int out_size, void* d_ws, size_t ws_size,
                              hipStream_t stream) {
    const int*   x_idx = (const int*)  d_in[0];
    const float* emb   = (const float*)d_in[1];
    const float* Wih1  = (const float*)d_in[2];
    const float* Whh1  = (const float*)d_in[3];
    const float* bih1  = (const float*)d_in[4];
    const float* bhh1  = (const float*)d_in[5];
    const float* Wih2  = (const float*)d_in[6];
    const float* Whh2  = (const float*)d_in[7];
    const float* bih2  = (const float*)d_in[8];
    const float* bhh2  = (const float*)d_in[9];
    const float* fcw   = (const float*)d_in[10];
    const float* fcb   = (const float*)d_in[11];
    float* out = (float*)d_out;

    float* table = (float*)d_ws;                       // 21*268*4 = 22512 B
    float* x2    = (float*)((char*)d_ws + 32768);      // 1024*100*64*4 = 26.2 MB

    k_table<<<VOCAB, 256, 0, stream>>>(Wih1, emb, bih1, bhh1, table);
    k_lstm1<<<NB / 4, 512, 0, stream>>>(x_idx, Whh1, table, x2);
    k_lstm2<<<NB / 4, 512, 0, stream>>>(x2, Wih2, Whh2, bih2, bhh2, fcw, fcb, out);
}

// Round 5
// 440.194 us; speedup vs baseline: 1.3287x; 1.3287x over previous
//
#include <hip/hip_runtime.h>

#define VOCAB 21
#define EMB 128
#define H1 64
#define H2 100
#define T1 500
#define TP 100
#define NB 1024
#define TBL_LD 268

typedef __attribute__((ext_vector_type(8))) short bf16x8;
typedef __attribute__((ext_vector_type(4))) float f32x4;

__device__ __forceinline__ float sigf(float x){ return 1.0f/(1.0f+__expf(-x)); }
__device__ __forceinline__ float tanhf_(float x){ return 1.0f - 2.0f/(1.0f+__expf(2.0f*x)); }
__device__ __forceinline__ unsigned short f2bf(float x){
    union { float f; unsigned u; } v; v.f = x;
    return (unsigned short)((v.u + 0x8000u) >> 16);
}
// LDS-only barrier: do NOT drain vmcnt (global stores fly async past it)
__device__ __forceinline__ void bar_lds(){
    asm volatile("s_waitcnt lgkmcnt(0)\n\ts_barrier" ::: "memory");
}
__device__ __forceinline__ void wait_lds(){
    asm volatile("s_waitcnt lgkmcnt(0)" ::: "memory");
}

// ---------------------------------------------------------------------------
// Kernel 0: permuted xproj table. table[v][4*cell+gate] =
//   dot(W_ih1[gate*64+cell,:], emb[v,:]) + b_ih1[..] + b_hh1[..]
// ---------------------------------------------------------------------------
__global__ void k_table(const float* __restrict__ Wih, const float* __restrict__ emb,
                        const float* __restrict__ bih, const float* __restrict__ bhh,
                        float* __restrict__ table){
    const int p = threadIdx.x;
    const int v = blockIdx.x;
    const int orig = (p & 3) * H1 + (p >> 2);
    float s = bih[orig] + bhh[orig];
    if (v != 0){
        const float* w = Wih + orig * EMB;
        const float* e = emb + v * EMB;
        #pragma unroll 16
        for (int d = 0; d < EMB; ++d) s += w[d]*e[d];
    }
    table[v*TBL_LD + p] = s;
}

// ---------------------------------------------------------------------------
// Kernel 1: layer-1 LSTM. 2 rows/block, 512 blocks (2 blocks/CU), 4 waves.
// Wave w owns gate tiles 4w..4w+3. After MFMA, producer lanes (batch col<2)
// write real acc quads to wave-private LDS; each lane reads back ONE quad ->
// exactly 1 cell update per lane per step (was 2 + 75% junk).
// ---------------------------------------------------------------------------
__global__ __launch_bounds__(256, 2) void k_lstm1(
    const int* __restrict__ xidx, const float* __restrict__ Whh,
    const float* __restrict__ tbl_g, float* __restrict__ x2){
  __shared__ __align__(16) float table[VOCAB*TBL_LD];        // 22512 B
  __shared__ __align__(16) unsigned short hbuf[2][16*64];    // 4096 B
  __shared__ __align__(16) f32x4 glds[4*64];                 // 4096 B, wave-private
  __shared__ int idxs[2*T1];                                 // 4000 B

  const int tid = threadIdx.x;
  const int w = tid >> 6, l = tid & 63;
  const int b0 = blockIdx.x * 2;
  const int n = l & 15, kg = l >> 4;

  for (int i = tid; i < VOCAB*TBL_LD; i += 256) table[i] = tbl_g[i];
  for (int i = tid; i < 2*T1; i += 256){
      int r = i / T1, t = i - r*T1;
      idxs[i] = xidx[(b0 + r)*T1 + t];
  }
  { unsigned* hz = (unsigned*)hbuf;                          // zero both h buffers
    for (int i = tid; i < 1024; i += 256) hz[i] = 0; }
  { float* gz = (float*)glds;                                // zero junk slots
    for (int i = tid; i < 1024; i += 256) gz[i] = 0.f; }

  // A fragments: tiles 4w+u; lane holds A row m=n, k = 32c + 8kg + j
  bf16x8 af[4][2];
  #pragma unroll
  for (int u = 0; u < 4; ++u){
      const int p = 16*(4*w + u) + n;
      const int orig = (p & 3)*H1 + (p >> 2);
      #pragma unroll
      for (int c = 0; c < 2; ++c){
          const float* src = Whh + orig*H1 + c*32 + kg*8;
          bf16x8 f;
          #pragma unroll
          for (int jj = 0; jj < 8; ++jj) f[jj] = (short)f2bf(src[jj]);
          af[u][c] = f;
      }
  }

  char* hb = (char*)hbuf;
  const int swz = (n & 7) << 4;
  const int rb0 = (n*128 + 16*kg) ^ swz;
  const int rb1 = (n*128 + 64 + 16*kg) ^ swz;
  // consumer mapping: lane l<32 owns (cell = 16w + l>>1, row = l&1)
  const int cell = 16*w + (l >> 1);
  const int r_c  = l & 1;
  const int wbh  = (r_c*128 + 2*cell) ^ (r_c << 4);
  const int rowc = n & 1;                      // tv clamp (junk cols 2..15)

  float cc = 0.f, pm = -1e30f;
  __syncthreads();

  int v0 = idxs[rowc*T1];
  f32x4 tv0 = *(const f32x4*)&table[v0*TBL_LD + 4*(16*w + 0  + kg)];
  f32x4 tv1 = *(const f32x4*)&table[v0*TBL_LD + 4*(16*w + 4  + kg)];
  f32x4 tv2 = *(const f32x4*)&table[v0*TBL_LD + 4*(16*w + 8  + kg)];
  f32x4 tv3 = *(const f32x4*)&table[v0*TBL_LD + 4*(16*w + 12 + kg)];

  int rp = 0, tm = 0;
  for (int t = 0; t < T1; ++t){
      bf16x8 bf0 = *(const bf16x8*)(hb + rp + rb0);
      bf16x8 bf1 = *(const bf16x8*)(hb + rp + rb1);
      f32x4 a0 = __builtin_amdgcn_mfma_f32_16x16x32_bf16(af[0][0], bf0, tv0, 0,0,0);
      a0       = __builtin_amdgcn_mfma_f32_16x16x32_bf16(af[0][1], bf1, a0, 0,0,0);
      f32x4 a1 = __builtin_amdgcn_mfma_f32_16x16x32_bf16(af[1][0], bf0, tv1, 0,0,0);
      a1       = __builtin_amdgcn_mfma_f32_16x16x32_bf16(af[1][1], bf1, a1, 0,0,0);
      f32x4 a2 = __builtin_amdgcn_mfma_f32_16x16x32_bf16(af[2][0], bf0, tv2, 0,0,0);
      a2       = __builtin_amdgcn_mfma_f32_16x16x32_bf16(af[2][1], bf1, a2, 0,0,0);
      f32x4 a3 = __builtin_amdgcn_mfma_f32_16x16x32_bf16(af[3][0], bf0, tv3, 0,0,0);
      a3       = __builtin_amdgcn_mfma_f32_16x16x32_bf16(af[3][1], bf1, a3, 0,0,0);
      if (t + 1 < T1){                       // prefetch next xproj (idx-only dep)
          int vn = idxs[rowc*T1 + t + 1];
          tv0 = *(const f32x4*)&table[vn*TBL_LD + 4*(16*w + 0  + kg)];
          tv1 = *(const f32x4*)&table[vn*TBL_LD + 4*(16*w + 4  + kg)];
          tv2 = *(const f32x4*)&table[vn*TBL_LD + 4*(16*w + 8  + kg)];
          tv3 = *(const f32x4*)&table[vn*TBL_LD + 4*(16*w + 12 + kg)];
      }
      // redistribute: slot(u) = (4u+kg)*2 + n  (wave-private, no barrier)
      if (n < 2){
          f32x4* gw = &glds[w*64 + kg*2 + n];
          gw[0]  = a0;
          gw[8]  = a1;
          gw[16] = a2;
          gw[24] = a3;
      }
      wait_lds();
      f32x4 g = glds[w*64 + l];              // lanes >=32 read zeroed junk
      cc = sigf(g[1])*cc + sigf(g[0])*tanhf_(g[2]);
      float hv = sigf(g[3])*tanhf_(cc);
      const int wp = rp ^ 2048;
      if (l < 32) *(unsigned short*)(hb + wp + wbh) = f2bf(hv);
      pm = fmaxf(pm, hv);
      if (++tm == 5){
          if (l < 32)
              x2[(b0 + r_c)*(TP*H1) + (t/5)*H1 + cell] = pm;  // async store
          pm = -1e30f; tm = 0;
      }
      rp = wp;
      bar_lds();
  }
}

// ---------------------------------------------------------------------------
// Kernel 2: layer-2 LSTM. 4 rows/block, 256 blocks, 8 waves; 26 gate tiles
// split 4,4,3,3,3,3,3,3. Same compress: 1 cell update/lane (was 3-4).
// B = [x(64) | h(100 pad 128)] bf16 ping-pong; stagers = waves 6,7.
// ---------------------------------------------------------------------------
__global__ __launch_bounds__(512, 2) void k_lstm2(
    const float* __restrict__ x2, const float* __restrict__ Wih,
    const float* __restrict__ Whh, const float* __restrict__ bih,
    const float* __restrict__ bhh, const float* __restrict__ fcw,
    const float* __restrict__ fcb, float* __restrict__ out){
  __shared__ __align__(16) unsigned short blds[2][16*192];   // 12288 B
  __shared__ __align__(16) f32x4 gl2[8*64];                  // 8192 B
  __shared__ float fcred[8][4];

  const int tid = threadIdx.x;
  const int w = tid >> 6, l = tid & 63;
  const int b0 = blockIdx.x * 4;
  const int n = l & 15, kg = l >> 4;
  const int tlo = (w < 2) ? 4*w : 8 + 3*(w - 2);
  const int nt  = (w < 2) ? 4 : 3;

  { unsigned* bz0 = (unsigned*)blds;                         // zero both buffers
    for (int i = tid; i < 3072; i += 512) bz0[i] = 0; }
  { float* gz = (float*)gl2;
    for (int i = tid; i < 2048; i += 512) gz[i] = 0.f; }

  // A fragments: [W_ih2 | W_hh2] permuted, zero-padded (k>=164 or cell>=100)
  bf16x8 af[4][6];
  #pragma unroll
  for (int u = 0; u < 4; ++u){
      if (u < nt){
          const int p = 16*(tlo + u) + n;
          const int cell_ = p >> 2, gate = p & 3;
          #pragma unroll
          for (int c = 0; c < 6; ++c){
              bf16x8 f;
              #pragma unroll
              for (int jj = 0; jj < 8; ++jj){
                  int k = c*32 + kg*8 + jj;
                  float vv = 0.f;
                  if (cell_ < H2){
                      if (k < 64)           vv = Wih[(gate*H2 + cell_)*H1 + k];
                      else if (k < 64 + H2) vv = Whh[(gate*H2 + cell_)*H2 + (k - 64)];
                  }
                  f[jj] = (short)f2bf(vv);
              }
              af[u][c] = f;
          }
      }
  }

  // bias C-init quads (producer layout: p = 16(tlo+u)+4kg+reg)
  f32x4 bz[4];
  #pragma unroll
  for (int u = 0; u < 4; ++u){
      const int cu = 4*(tlo + u) + kg;
      f32x4 b = {0.f,0.f,0.f,0.f};
      if (u < nt && cu < H2){
          #pragma unroll
          for (int g = 0; g < 4; ++g) b[g] = bih[g*H2 + cu] + bhh[g*H2 + cu];
      }
      bz[u] = b;
  }

  // consumer mapping: lane l owns (cell = 4*tlo + l>>2, row = l&3)
  const bool act = (l >> 2) < 4*nt;
  const int cellc = 4*tlo + (l >> 2);
  const int r_c = l & 3;
  float fwv = 0.f;
  if (act && cellc < H2) fwv = fcw[cellc];

  char* bb = (char*)blds;
  const int swz = (n & 7) << 4;
  int rb[6];
  #pragma unroll
  for (int c = 0; c < 6; ++c) rb[c] = (n*384 + 64*c + 16*kg) ^ swz;
  const int wbh = (r_c*384 + 2*(64 + cellc)) ^ (r_c << 4);

  // x-staging: waves 6,7 (tid>=384): row xr, cells 2*xc, 2*xc+1
  const int xr = (tid >> 5) & 3, xc = tid & 31;
  const int xwb = (xr*384 + 4*xc) ^ (xr << 4);
  if (tid >= 384){
      float2 v = *(const float2*)&x2[(b0 + xr)*(TP*H1) + 2*xc];
      unsigned pk = (unsigned)f2bf(v.x) | ((unsigned)f2bf(v.y) << 16);
      *(unsigned*)(bb + xwb) = pk;
  }
  float cc = 0.f, hv = 0.f;
  __syncthreads();

  int rp = 0;
  for (int t = 0; t < TP; ++t){
      float2 xn = {0.f, 0.f};
      if (tid >= 384 && t + 1 < TP)              // T14 issue-early
          xn = *(const float2*)&x2[(b0 + xr)*(TP*H1) + (t+1)*H1 + 2*xc];
      bf16x8 bf[6];
      #pragma unroll
      for (int c = 0; c < 6; ++c) bf[c] = *(const bf16x8*)(bb + rp + rb[c]);
      #pragma unroll
      for (int u = 0; u < 4; ++u){
          if (u < nt){
              f32x4 z = bz[u];
              #pragma unroll
              for (int c = 0; c < 6; ++c)
                  z = __builtin_amdgcn_mfma_f32_16x16x32_bf16(af[u][c], bf[c], z, 0,0,0);
              if (n < 4) gl2[w*64 + kg*4 + n + 16*u] = z;   // slot (4u+kg)*4+n
          }
      }
      wait_lds();
      f32x4 g = gl2[w*64 + l];
      cc = sigf(g[1])*cc + sigf(g[0])*tanhf_(g[2]);
      hv = sigf(g[3])*tanhf_(cc);
      const int wp = rp ^ 6144;
      if (act) *(unsigned short*)(bb + wp + wbh) = f2bf(hv);  // zero-weight cols protect cells>=100
      if (tid >= 384 && t + 1 < TP){             // write-late
          unsigned pk = (unsigned)f2bf(xn.x) | ((unsigned)f2bf(xn.y) << 16);
          *(unsigned*)(bb + wp + xwb) = pk;
      }
      rp = wp;
      bar_lds();
  }

  // FC + sigmoid: sum over cells for fixed row (lanes with same l&3), then waves
  float p = hv * fwv;
  p += __shfl_xor(p, 4);
  p += __shfl_xor(p, 8);
  p += __shfl_xor(p, 16);
  p += __shfl_xor(p, 32);
  if (l < 4) fcred[w][l] = p;
  __syncthreads();
  if (tid < 4){
      float s = 0.f;
      #pragma unroll
      for (int ww = 0; ww < 8; ++ww) s += fcred[ww][tid];
      out[b0 + tid] = sigf(s + fcb[0]);
  }
}

// ---------------------------------------------------------------------------
extern "C" void kernel_launch(void* const* d_in, const int* in_sizes, int n_in,
                              void* d_out, int out_size, void* d_ws, size_t ws_size,
                              hipStream_t stream) {
    const int*   x_idx = (const int*)  d_in[0];
    const float* emb   = (const float*)d_in[1];
    const float* Wih1  = (const float*)d_in[2];
    const float* Whh1  = (const float*)d_in[3];
    const float* bih1  = (const float*)d_in[4];
    const float* bhh1  = (const float*)d_in[5];
    const float* Wih2  = (const float*)d_in[6];
    const float* Whh2  = (const float*)d_in[7];
    const float* bih2  = (const float*)d_in[8];
    const float* bhh2  = (const float*)d_in[9];
    const float* fcw   = (const float*)d_in[10];
    const float* fcb   = (const float*)d_in[11];
    float* out = (float*)d_out;

    float* table = (float*)d_ws;                       // 21*268*4 = 22512 B
    float* x2    = (float*)((char*)d_ws + 32768);      // 1024*100*64*4 = 26.2 MB

    k_table<<<VOCAB, 256, 0, stream>>>(Wih1, emb, bih1, bhh1, table);
    k_lstm1<<<NB / 2, 256, 0, stream>>>(x_idx, Whh1, table, x2);
    k_lstm2<<<NB / 4, 512, 0, stream>>>(x2, Wih2, Whh2, bih2, bhh2, fcw, fcb, out);
}